// Round 1
// baseline (1743.468 us; speedup 1.0000x reference)
//
#include <hip/hip_runtime.h>
#include <cstdint>

#define D 128
#define SW_STRIDE 132
#define SA_STRIDE 68

__device__ __forceinline__ float elu_f(float x) {
    return x > 0.0f ? x : __expf(x) - 1.0f;
}

// ---------------- CSR build (by dst), reused across all 4 layers ----------------
__global__ void hist_kernel(const int* __restrict__ dst, int* __restrict__ deg, int E) {
    int e = blockIdx.x * blockDim.x + threadIdx.x;
    if (e < E) atomicAdd(&deg[dst[e]], 1);
}

__global__ void scan_kernel(const int* __restrict__ deg, int* __restrict__ rowptr,
                            int* __restrict__ cursor, int N, int E) {
    __shared__ int ssum[1024];
    int t = threadIdx.x;
    int chunk = (N + 1023) / 1024;
    int begin = t * chunk;
    int end = begin + chunk; if (end > N) end = N; if (begin > N) begin = N;
    int s = 0;
    for (int i = begin; i < end; ++i) s += deg[i];
    ssum[t] = s;
    __syncthreads();
    for (int off = 1; off < 1024; off <<= 1) {
        int v = (t >= off) ? ssum[t - off] : 0;
        __syncthreads();
        ssum[t] += v;
        __syncthreads();
    }
    int prefix = (t == 0) ? 0 : ssum[t - 1];
    for (int i = begin; i < end; ++i) {
        rowptr[i] = prefix;
        cursor[i] = prefix;
        prefix += deg[i];
    }
    if (t == 1023) rowptr[N] = E;
}

__global__ void fill_kernel(const int* __restrict__ src, const int* __restrict__ dst,
                            int* __restrict__ cursor, int* __restrict__ col, int E) {
    int e = blockIdx.x * blockDim.x + threadIdx.x;
    if (e < E) {
        int pos = atomicAdd(&cursor[dst[e]], 1);
        col[pos] = src[e];
    }
}

// ---------------- GIN aggregation: out[i] = h[i] + sum_{j in N(i)} h[j] ----------------
__global__ __launch_bounds__(128) void aggregate_kernel(
    const float* __restrict__ h, const int* __restrict__ rowptr,
    const int* __restrict__ col, float* __restrict__ out) {
    int i = blockIdx.x;
    int c = threadIdx.x;
    int e0 = rowptr[i], e1 = rowptr[i + 1];
    float acc = h[(size_t)i * D + c];
    int e = e0;
    for (; e + 1 < e1; e += 2) {
        int j0 = col[e], j1 = col[e + 1];
        float v0 = h[(size_t)j0 * D + c];
        float v1 = h[(size_t)j1 * D + c];
        acc += v0 + v1;
    }
    if (e < e1) acc += h[(size_t)col[e] * D + c];
    out[(size_t)i * D + c] = acc;
}

// ---------------- Fused GEMM: out = [elu?](in' @ W + bias), in' = TRANS ? elu(in*scale+shift) : in
// in: [N,128], W: [128,128] row-major (z[c] = sum_k in[k] * W[k][c])
template <bool TRANS, bool ELU_OUT>
__global__ __launch_bounds__(256) void gemm_kernel(
    const float* __restrict__ in, const float* __restrict__ W,
    const float* __restrict__ bias, const float* __restrict__ scale,
    const float* __restrict__ shift, float* __restrict__ out, int N) {
    __shared__ float sW[64 * SW_STRIDE];
    __shared__ float sA[64 * SA_STRIDE];
    const int tid = threadIdx.x;
    const int row0 = blockIdx.x * 64;
    const int tr4 = (tid >> 4) * 4;   // 16 row groups * 4 rows
    const int tc8 = (tid & 15) * 8;   // 16 col groups * 8 cols
    float acc[4][8] = {};

    for (int kb = 0; kb < 128; kb += 64) {
        __syncthreads();
        // stage W half: 64 (k) x 128 (c) = 2048 float4, 8 per thread
#pragma unroll
        for (int it = 0; it < 8; ++it) {
            int idx = tid + it * 256;
            int kr = idx >> 5;        // 0..63
            int f4 = idx & 31;        // 0..31
            float4 w = *(const float4*)&W[(size_t)(kb + kr) * D + f4 * 4];
            *(float4*)&sW[kr * SW_STRIDE + f4 * 4] = w;
        }
        // stage A tile: 64 rows x 64 k = 1024 float4, 4 per thread
#pragma unroll
        for (int it = 0; it < 4; ++it) {
            int idx = tid + it * 256;
            int r = idx >> 4;         // 0..63
            int f4 = idx & 15;        // 0..15
            int gr = row0 + r;
            float4 a;
            if (gr < N) {
                a = *(const float4*)&in[(size_t)gr * D + kb + f4 * 4];
                if (TRANS) {
                    float4 sc = *(const float4*)&scale[kb + f4 * 4];
                    float4 sh = *(const float4*)&shift[kb + f4 * 4];
                    a.x = elu_f(a.x * sc.x + sh.x);
                    a.y = elu_f(a.y * sc.y + sh.y);
                    a.z = elu_f(a.z * sc.z + sh.z);
                    a.w = elu_f(a.w * sc.w + sh.w);
                }
            } else {
                a = make_float4(0.f, 0.f, 0.f, 0.f);
            }
            *(float4*)&sA[r * SA_STRIDE + f4 * 4] = a;
        }
        __syncthreads();

#pragma unroll 4
        for (int k0 = 0; k0 < 64; k0 += 4) {
            float4 a4[4];
#pragma unroll
            for (int i = 0; i < 4; ++i)
                a4[i] = *(const float4*)&sA[(tr4 + i) * SA_STRIDE + k0];
#pragma unroll
            for (int kq = 0; kq < 4; ++kq) {
                float4 w0 = *(const float4*)&sW[(k0 + kq) * SW_STRIDE + tc8];
                float4 w1 = *(const float4*)&sW[(k0 + kq) * SW_STRIDE + tc8 + 4];
#pragma unroll
                for (int i = 0; i < 4; ++i) {
                    float av = ((const float*)&a4[i])[kq];
                    acc[i][0] += av * w0.x;
                    acc[i][1] += av * w0.y;
                    acc[i][2] += av * w0.z;
                    acc[i][3] += av * w0.w;
                    acc[i][4] += av * w1.x;
                    acc[i][5] += av * w1.y;
                    acc[i][6] += av * w1.z;
                    acc[i][7] += av * w1.w;
                }
            }
        }
    }

    float4 b0 = *(const float4*)&bias[tc8];
    float4 b1v = *(const float4*)&bias[tc8 + 4];
#pragma unroll
    for (int i = 0; i < 4; ++i) {
        int gr = row0 + tr4 + i;
        if (gr < N) {
            float v[8];
            v[0] = acc[i][0] + b0.x; v[1] = acc[i][1] + b0.y;
            v[2] = acc[i][2] + b0.z; v[3] = acc[i][3] + b0.w;
            v[4] = acc[i][4] + b1v.x; v[5] = acc[i][5] + b1v.y;
            v[6] = acc[i][6] + b1v.z; v[7] = acc[i][7] + b1v.w;
            if (ELU_OUT) {
#pragma unroll
                for (int j = 0; j < 8; ++j) v[j] = elu_f(v[j]);
            }
            float4 o0 = make_float4(v[0], v[1], v[2], v[3]);
            float4 o1 = make_float4(v[4], v[5], v[6], v[7]);
            *(float4*)&out[(size_t)gr * D + tc8] = o0;
            *(float4*)&out[(size_t)gr * D + tc8 + 4] = o1;
        }
    }
}

// ---------------- BatchNorm stats: per-column sum and sumsq ----------------
__global__ __launch_bounds__(128) void bn_stats_kernel(
    const float* __restrict__ z, float* __restrict__ sums, int N) {
    int c = threadIdx.x;
    int r0 = blockIdx.x * 128;
    int rend = r0 + 128; if (rend > N) rend = N;
    float s = 0.f, s2 = 0.f;
    for (int r = r0; r < rend; ++r) {
        float v = z[(size_t)r * D + c];
        s += v;
        s2 += v * v;
    }
    atomicAdd(&sums[c], s);
    atomicAdd(&sums[D + c], s2);
}

__global__ void bn_finalize_kernel(const float* __restrict__ sums,
                                   const float* __restrict__ gamma,
                                   const float* __restrict__ beta,
                                   float* __restrict__ scale, float* __restrict__ shift,
                                   int N) {
    int c = threadIdx.x;
    float invN = 1.0f / (float)N;
    float mu = sums[c] * invN;
    float var = sums[D + c] * invN - mu * mu;
    float rs = rsqrtf(var + 1e-5f);
    float sc = gamma[c] * rs;
    scale[c] = sc;
    shift[c] = beta[c] - mu * sc;
}

// ---------------- global mean pool (batch sorted -> run-length + atomics) ----------------
__global__ __launch_bounds__(128) void pool_kernel(
    const float* __restrict__ h, const int* __restrict__ batch,
    float* __restrict__ pooled, float* __restrict__ cnt, int N) {
    int c = threadIdx.x;
    int r0 = blockIdx.x * 256;
    if (r0 >= N) return;
    int rend = r0 + 256; if (rend > N) rend = N;
    int cur = batch[r0];
    float acc = 0.f;
    float cacc = 0.f;
    for (int r = r0; r < rend; ++r) {
        int b = batch[r];
        if (b != cur) {
            atomicAdd(&pooled[(size_t)cur * D + c], acc);
            if (c == 0) atomicAdd(&cnt[cur], cacc);
            acc = 0.f; cacc = 0.f; cur = b;
        }
        acc += h[(size_t)r * D + c];
        cacc += 1.f;
    }
    atomicAdd(&pooled[(size_t)cur * D + c], acc);
    if (c == 0) atomicAdd(&cnt[cur], cacc);
}

__global__ void final_linear_kernel(const float* __restrict__ pooled,
                                    const float* __restrict__ cnt,
                                    const float* __restrict__ linW,
                                    const float* __restrict__ linb,
                                    float* __restrict__ out, int G) {
    int t = blockIdx.x * blockDim.x + threadIdx.x;
    if (t >= G * 2) return;
    int g = t >> 1, o = t & 1;
    float inv = 1.0f / fmaxf(cnt[g], 1.0f);
    float s = linb[o];
    for (int c = 0; c < D; ++c)
        s += pooled[(size_t)g * D + c] * inv * linW[c * 2 + o];
    out[t] = s;
}

extern "C" void kernel_launch(void* const* d_in, const int* in_sizes, int n_in,
                              void* d_out, int out_size, void* d_ws, size_t ws_size,
                              hipStream_t stream) {
    const float* x      = (const float*)d_in[0];
    const int*  eidx    = (const int*)d_in[1];
    const int*  batch   = (const int*)d_in[2];
    const float* W1     = (const float*)d_in[3];
    const float* b1     = (const float*)d_in[4];
    const float* gamma  = (const float*)d_in[5];
    const float* beta   = (const float*)d_in[6];
    const float* W2     = (const float*)d_in[7];
    const float* b2     = (const float*)d_in[8];
    const float* linW   = (const float*)d_in[9];
    const float* linb   = (const float*)d_in[10];
    float* out = (float*)d_out;

    const int N = in_sizes[0] / D;
    const int E = in_sizes[1] / 2;
    const int L = in_sizes[3] / (D * D);
    const int G = out_size / 2;
    const int* esrc = eidx;
    const int* edst = eidx + E;

    // workspace carve-up
    size_t off = 0;
    auto carve = [&](size_t bytes) -> void* {
        void* p = (char*)d_ws + off;
        off += (bytes + 255) & ~(size_t)255;
        return p;
    };
    const size_t ND = (size_t)N * D;
    float* agg    = (float*)carve(ND * 4);
    float* z1     = (float*)carve(ND * 4);
    float* hbuf   = (float*)carve(ND * 4);
    int* deg      = (int*)carve((size_t)N * 4);
    int* rowptr   = (int*)carve((size_t)(N + 1) * 4);
    int* cursor   = (int*)carve((size_t)N * 4);
    int* col      = (int*)carve((size_t)E * 4);
    float* colsum = (float*)carve(2 * D * 4);   // sums + sumsq
    float* scale  = (float*)carve(D * 4);
    float* shift  = (float*)carve(D * 4);
    float* pooled = (float*)carve((size_t)G * D * 4);
    float* cnt    = (float*)carve((size_t)G * 4);
    (void)ws_size; (void)n_in;

    // ---- CSR build (once per launch) ----
    hipMemsetAsync(deg, 0, (size_t)N * 4, stream);
    hist_kernel<<<(E + 255) / 256, 256, 0, stream>>>(edst, deg, E);
    scan_kernel<<<1, 1024, 0, stream>>>(deg, rowptr, cursor, N, E);
    fill_kernel<<<(E + 255) / 256, 256, 0, stream>>>(esrc, edst, cursor, col, E);

    const int gemm_grid = (N + 63) / 64;
    const float* hin = x;
    for (int l = 0; l < L; ++l) {
        aggregate_kernel<<<N, 128, 0, stream>>>(hin, rowptr, col, agg);
        gemm_kernel<false, false><<<gemm_grid, 256, 0, stream>>>(
            agg, W1 + (size_t)l * D * D, b1 + (size_t)l * D, nullptr, nullptr, z1, N);
        hipMemsetAsync(colsum, 0, 2 * D * 4, stream);
        bn_stats_kernel<<<(N + 127) / 128, 128, 0, stream>>>(z1, colsum, N);
        bn_finalize_kernel<<<1, D, 0, stream>>>(colsum, gamma + (size_t)l * D,
                                                beta + (size_t)l * D, scale, shift, N);
        gemm_kernel<true, true><<<gemm_grid, 256, 0, stream>>>(
            z1, W2 + (size_t)l * D * D, b2 + (size_t)l * D, scale, shift, hbuf, N);
        hin = hbuf;
    }

    // ---- pooling + final linear ----
    hipMemsetAsync(pooled, 0, (size_t)G * D * 4, stream);
    hipMemsetAsync(cnt, 0, (size_t)G * 4, stream);
    pool_kernel<<<(N + 255) / 256, 128, 0, stream>>>(hbuf, batch, pooled, cnt, N);
    final_linear_kernel<<<(G * 2 + 255) / 256, 256, 0, stream>>>(pooled, cnt, linW, linb, out, G);
}

// Round 2
// 1542.730 us; speedup vs baseline: 1.1301x; 1.1301x over previous
//
#include <hip/hip_runtime.h>
#include <cstdint>

#define D 128
#define SW_STRIDE 132
#define SA_STRIDE 68
#define SCAN_CHUNK 2048

__device__ __forceinline__ float elu_f(float x) {
    return x > 0.0f ? x : __expf(x) - 1.0f;
}

// ---------------- CSR build (by dst), reused across all 4 layers ----------------
__global__ void hist_kernel(const int* __restrict__ dst, int* __restrict__ deg, int E) {
    int e = blockIdx.x * blockDim.x + threadIdx.x;
    if (e < E) atomicAdd(&deg[dst[e]], 1);
}

// Phase A: per-block partial sums of deg (2048 elements / block)
__global__ __launch_bounds__(256) void scan_partial_kernel(
    const int* __restrict__ deg, int* __restrict__ blocksum, int N) {
    __shared__ int red[256];
    int t = threadIdx.x;
    int base = blockIdx.x * SCAN_CHUNK;
    int s = 0;
#pragma unroll
    for (int i = 0; i < 8; ++i) {
        int idx = base + i * 256 + t;
        if (idx < N) s += deg[idx];
    }
    red[t] = s;
    __syncthreads();
    for (int off = 128; off > 0; off >>= 1) {
        if (t < off) red[t] += red[t + off];
        __syncthreads();
    }
    if (t == 0) blocksum[blockIdx.x] = red[0];
}

// Phase B: exclusive scan of block sums (small: ~49 entries) + rowptr[N]=E
__global__ void scan_sums_kernel(int* __restrict__ blocksum, int PB,
                                 int* __restrict__ rowptr, int N, int E) {
    if (threadIdx.x == 0) {
        int run = 0;
        for (int i = 0; i < PB; ++i) {
            int v = blocksum[i];
            blocksum[i] = run;
            run += v;
        }
        rowptr[N] = E;
    }
}

// Phase C: per-block local scan -> rowptr & cursor
__global__ __launch_bounds__(256) void scan_fill_kernel(
    const int* __restrict__ deg, const int* __restrict__ blocksum,
    int* __restrict__ rowptr, int* __restrict__ cursor, int N) {
    __shared__ int tsum[256];
    int t = threadIdx.x;
    int base = blockIdx.x * SCAN_CHUNK + t * 8;
    int local[8];
    int s = 0;
#pragma unroll
    for (int i = 0; i < 8; ++i) {
        int idx = base + i;
        local[i] = (idx < N) ? deg[idx] : 0;
        s += local[i];
    }
    tsum[t] = s;
    __syncthreads();
    // Hillis-Steele inclusive scan over 256 thread sums
    for (int off = 1; off < 256; off <<= 1) {
        int v = (t >= off) ? tsum[t - off] : 0;
        __syncthreads();
        tsum[t] += v;
        __syncthreads();
    }
    int prefix = blocksum[blockIdx.x] + ((t == 0) ? 0 : tsum[t - 1]);
#pragma unroll
    for (int i = 0; i < 8; ++i) {
        int idx = base + i;
        if (idx < N) {
            rowptr[idx] = prefix;
            cursor[idx] = prefix;
            prefix += local[i];
        }
    }
}

__global__ void fill_kernel(const int* __restrict__ src, const int* __restrict__ dst,
                            int* __restrict__ cursor, int* __restrict__ col, int E) {
    int e = blockIdx.x * blockDim.x + threadIdx.x;
    if (e < E) {
        int pos = atomicAdd(&cursor[dst[e]], 1);
        col[pos] = src[e];
    }
}

// ---------------- GIN aggregation: out[i] = h[i] + sum_{j in N(i)} h[j] ----------------
// float4 lanes: 32 lanes per node, 8 nodes per 256-thread block
__global__ __launch_bounds__(256) void aggregate_kernel(
    const float* __restrict__ h, const int* __restrict__ rowptr,
    const int* __restrict__ col, float* __restrict__ out, int N) {
    int node = blockIdx.x * 8 + (threadIdx.x >> 5);
    int q = threadIdx.x & 31;
    if (node >= N) return;
    const float4* h4 = (const float4*)h;
    int e0 = rowptr[node], e1 = rowptr[node + 1];
    float4 acc = h4[(size_t)node * 32 + q];
    int e = e0;
    for (; e + 1 < e1; e += 2) {
        int j0 = col[e], j1 = col[e + 1];
        float4 v0 = h4[(size_t)j0 * 32 + q];
        float4 v1 = h4[(size_t)j1 * 32 + q];
        acc.x += v0.x + v1.x;
        acc.y += v0.y + v1.y;
        acc.z += v0.z + v1.z;
        acc.w += v0.w + v1.w;
    }
    if (e < e1) {
        float4 v = h4[(size_t)col[e] * 32 + q];
        acc.x += v.x; acc.y += v.y; acc.z += v.z; acc.w += v.w;
    }
    ((float4*)out)[(size_t)node * 32 + q] = acc;
}

// ---------------- Fused GEMM: out = [elu?](in' @ W + bias), in' = TRANS ? elu(in*scale+shift) : in
template <bool TRANS, bool ELU_OUT>
__global__ __launch_bounds__(256) void gemm_kernel(
    const float* __restrict__ in, const float* __restrict__ W,
    const float* __restrict__ bias, const float* __restrict__ scale,
    const float* __restrict__ shift, float* __restrict__ out, int N) {
    __shared__ float sW[64 * SW_STRIDE];
    __shared__ float sA[64 * SA_STRIDE];
    const int tid = threadIdx.x;
    const int row0 = blockIdx.x * 64;
    const int tr4 = (tid >> 4) * 4;
    const int tc8 = (tid & 15) * 8;
    float acc[4][8] = {};

    for (int kb = 0; kb < 128; kb += 64) {
        __syncthreads();
#pragma unroll
        for (int it = 0; it < 8; ++it) {
            int idx = tid + it * 256;
            int kr = idx >> 5;
            int f4 = idx & 31;
            float4 w = *(const float4*)&W[(size_t)(kb + kr) * D + f4 * 4];
            *(float4*)&sW[kr * SW_STRIDE + f4 * 4] = w;
        }
#pragma unroll
        for (int it = 0; it < 4; ++it) {
            int idx = tid + it * 256;
            int r = idx >> 4;
            int f4 = idx & 15;
            int gr = row0 + r;
            float4 a;
            if (gr < N) {
                a = *(const float4*)&in[(size_t)gr * D + kb + f4 * 4];
                if (TRANS) {
                    float4 sc = *(const float4*)&scale[kb + f4 * 4];
                    float4 sh = *(const float4*)&shift[kb + f4 * 4];
                    a.x = elu_f(a.x * sc.x + sh.x);
                    a.y = elu_f(a.y * sc.y + sh.y);
                    a.z = elu_f(a.z * sc.z + sh.z);
                    a.w = elu_f(a.w * sc.w + sh.w);
                }
            } else {
                a = make_float4(0.f, 0.f, 0.f, 0.f);
            }
            *(float4*)&sA[r * SA_STRIDE + f4 * 4] = a;
        }
        __syncthreads();

#pragma unroll 4
        for (int k0 = 0; k0 < 64; k0 += 4) {
            float4 a4[4];
#pragma unroll
            for (int i = 0; i < 4; ++i)
                a4[i] = *(const float4*)&sA[(tr4 + i) * SA_STRIDE + k0];
#pragma unroll
            for (int kq = 0; kq < 4; ++kq) {
                float4 w0 = *(const float4*)&sW[(k0 + kq) * SW_STRIDE + tc8];
                float4 w1 = *(const float4*)&sW[(k0 + kq) * SW_STRIDE + tc8 + 4];
#pragma unroll
                for (int i = 0; i < 4; ++i) {
                    float av = ((const float*)&a4[i])[kq];
                    acc[i][0] += av * w0.x;
                    acc[i][1] += av * w0.y;
                    acc[i][2] += av * w0.z;
                    acc[i][3] += av * w0.w;
                    acc[i][4] += av * w1.x;
                    acc[i][5] += av * w1.y;
                    acc[i][6] += av * w1.z;
                    acc[i][7] += av * w1.w;
                }
            }
        }
    }

    float4 b0 = *(const float4*)&bias[tc8];
    float4 b1v = *(const float4*)&bias[tc8 + 4];
#pragma unroll
    for (int i = 0; i < 4; ++i) {
        int gr = row0 + tr4 + i;
        if (gr < N) {
            float v[8];
            v[0] = acc[i][0] + b0.x; v[1] = acc[i][1] + b0.y;
            v[2] = acc[i][2] + b0.z; v[3] = acc[i][3] + b0.w;
            v[4] = acc[i][4] + b1v.x; v[5] = acc[i][5] + b1v.y;
            v[6] = acc[i][6] + b1v.z; v[7] = acc[i][7] + b1v.w;
            if (ELU_OUT) {
#pragma unroll
                for (int j = 0; j < 8; ++j) v[j] = elu_f(v[j]);
            }
            *(float4*)&out[(size_t)gr * D + tc8] = make_float4(v[0], v[1], v[2], v[3]);
            *(float4*)&out[(size_t)gr * D + tc8 + 4] = make_float4(v[4], v[5], v[6], v[7]);
        }
    }
}

// ---------------- BatchNorm stats: per-column sum and sumsq ----------------
__global__ __launch_bounds__(128) void bn_stats_kernel(
    const float* __restrict__ z, float* __restrict__ sums, int N) {
    int c = threadIdx.x;
    int r0 = blockIdx.x * 128;
    int rend = r0 + 128; if (rend > N) rend = N;
    float s = 0.f, s2 = 0.f;
    for (int r = r0; r < rend; ++r) {
        float v = z[(size_t)r * D + c];
        s += v;
        s2 += v * v;
    }
    atomicAdd(&sums[c], s);
    atomicAdd(&sums[D + c], s2);
}

__global__ void bn_finalize_kernel(const float* __restrict__ sums,
                                   const float* __restrict__ gamma,
                                   const float* __restrict__ beta,
                                   float* __restrict__ scale, float* __restrict__ shift,
                                   int N) {
    int c = threadIdx.x;
    float invN = 1.0f / (float)N;
    float mu = sums[c] * invN;
    float var = sums[D + c] * invN - mu * mu;
    float rs = rsqrtf(var + 1e-5f);
    float sc = gamma[c] * rs;
    scale[c] = sc;
    shift[c] = beta[c] - mu * sc;
}

// ---------------- global mean pool (batch sorted -> run-length + atomics) ----------------
__global__ __launch_bounds__(128) void pool_kernel(
    const float* __restrict__ h, const int* __restrict__ batch,
    float* __restrict__ pooled, float* __restrict__ cnt, int N) {
    int c = threadIdx.x;
    int r0 = blockIdx.x * 256;
    if (r0 >= N) return;
    int rend = r0 + 256; if (rend > N) rend = N;
    int cur = batch[r0];
    float acc = 0.f;
    float cacc = 0.f;
    for (int r = r0; r < rend; ++r) {
        int b = batch[r];
        if (b != cur) {
            atomicAdd(&pooled[(size_t)cur * D + c], acc);
            if (c == 0) atomicAdd(&cnt[cur], cacc);
            acc = 0.f; cacc = 0.f; cur = b;
        }
        acc += h[(size_t)r * D + c];
        cacc += 1.f;
    }
    atomicAdd(&pooled[(size_t)cur * D + c], acc);
    if (c == 0) atomicAdd(&cnt[cur], cacc);
}

__global__ void final_linear_kernel(const float* __restrict__ pooled,
                                    const float* __restrict__ cnt,
                                    const float* __restrict__ linW,
                                    const float* __restrict__ linb,
                                    float* __restrict__ out, int G) {
    int t = blockIdx.x * blockDim.x + threadIdx.x;
    if (t >= G * 2) return;
    int g = t >> 1, o = t & 1;
    float inv = 1.0f / fmaxf(cnt[g], 1.0f);
    float s = linb[o];
    for (int c = 0; c < D; ++c)
        s += pooled[(size_t)g * D + c] * inv * linW[c * 2 + o];
    out[t] = s;
}

extern "C" void kernel_launch(void* const* d_in, const int* in_sizes, int n_in,
                              void* d_out, int out_size, void* d_ws, size_t ws_size,
                              hipStream_t stream) {
    const float* x      = (const float*)d_in[0];
    const int*  eidx    = (const int*)d_in[1];
    const int*  batch   = (const int*)d_in[2];
    const float* W1     = (const float*)d_in[3];
    const float* b1     = (const float*)d_in[4];
    const float* gamma  = (const float*)d_in[5];
    const float* beta   = (const float*)d_in[6];
    const float* W2     = (const float*)d_in[7];
    const float* b2     = (const float*)d_in[8];
    const float* linW   = (const float*)d_in[9];
    const float* linb   = (const float*)d_in[10];
    float* out = (float*)d_out;

    const int N = in_sizes[0] / D;
    const int E = in_sizes[1] / 2;
    const int L = in_sizes[3] / (D * D);
    const int G = out_size / 2;
    const int* esrc = eidx;
    const int* edst = eidx + E;

    size_t off = 0;
    auto carve = [&](size_t bytes) -> void* {
        void* p = (char*)d_ws + off;
        off += (bytes + 255) & ~(size_t)255;
        return p;
    };
    const size_t ND = (size_t)N * D;
    const int PB = (N + SCAN_CHUNK - 1) / SCAN_CHUNK;
    float* agg    = (float*)carve(ND * 4);
    float* z1     = (float*)carve(ND * 4);
    float* hbuf   = (float*)carve(ND * 4);
    int* deg      = (int*)carve((size_t)N * 4);
    int* rowptr   = (int*)carve((size_t)(N + 1) * 4);
    int* cursor   = (int*)carve((size_t)N * 4);
    int* col      = (int*)carve((size_t)E * 4);
    int* blocksum = (int*)carve((size_t)PB * 4);
    float* colsum = (float*)carve(2 * D * 4);
    float* scale  = (float*)carve(D * 4);
    float* shift  = (float*)carve(D * 4);
    float* pooled = (float*)carve((size_t)G * D * 4);
    float* cnt    = (float*)carve((size_t)G * 4);
    (void)ws_size; (void)n_in;

    // ---- CSR build ----
    hipMemsetAsync(deg, 0, (size_t)N * 4, stream);
    hist_kernel<<<(E + 255) / 256, 256, 0, stream>>>(edst, deg, E);
    scan_partial_kernel<<<PB, 256, 0, stream>>>(deg, blocksum, N);
    scan_sums_kernel<<<1, 64, 0, stream>>>(blocksum, PB, rowptr, N, E);
    scan_fill_kernel<<<PB, 256, 0, stream>>>(deg, blocksum, rowptr, cursor, N);
    fill_kernel<<<(E + 255) / 256, 256, 0, stream>>>(esrc, edst, cursor, col, E);

    const int gemm_grid = (N + 63) / 64;
    const int agg_grid = (N + 7) / 8;
    const float* hin = x;
    for (int l = 0; l < L; ++l) {
        aggregate_kernel<<<agg_grid, 256, 0, stream>>>(hin, rowptr, col, agg, N);
        gemm_kernel<false, false><<<gemm_grid, 256, 0, stream>>>(
            agg, W1 + (size_t)l * D * D, b1 + (size_t)l * D, nullptr, nullptr, z1, N);
        hipMemsetAsync(colsum, 0, 2 * D * 4, stream);
        bn_stats_kernel<<<(N + 127) / 128, 128, 0, stream>>>(z1, colsum, N);
        bn_finalize_kernel<<<1, D, 0, stream>>>(colsum, gamma + (size_t)l * D,
                                                beta + (size_t)l * D, scale, shift, N);
        gemm_kernel<true, true><<<gemm_grid, 256, 0, stream>>>(
            z1, W2 + (size_t)l * D * D, b2 + (size_t)l * D, scale, shift, hbuf, N);
        hin = hbuf;
    }

    hipMemsetAsync(pooled, 0, (size_t)G * D * 4, stream);
    hipMemsetAsync(cnt, 0, (size_t)G * 4, stream);
    pool_kernel<<<(N + 255) / 256, 128, 0, stream>>>(hbuf, batch, pooled, cnt, N);
    final_linear_kernel<<<(G * 2 + 255) / 256, 256, 0, stream>>>(pooled, cnt, linW, linb, out, G);
}

// Round 3
// 1338.641 us; speedup vs baseline: 1.3024x; 1.1525x over previous
//
#include <hip/hip_runtime.h>
#include <cstdint>

#define D 128
#define SCAN_CHUNK 2048

typedef __attribute__((ext_vector_type(8))) short short8;
typedef __attribute__((ext_vector_type(4))) float floatx4;

__device__ __forceinline__ float elu_f(float x) {
    return x > 0.0f ? x : __expf(x) - 1.0f;
}

// truncation split: a = hi + lo + O(2^-16 |a|), hi/lo bf16 bit patterns
__device__ __forceinline__ void split_bf16(float a, unsigned short& hi, unsigned short& lo) {
    unsigned u = __builtin_bit_cast(unsigned, a);
    unsigned hb = u & 0xffff0000u;
    float hf = __builtin_bit_cast(float, hb);
    float rl = a - hf;                       // exact
    unsigned ul = __builtin_bit_cast(unsigned, rl);
    hi = (unsigned short)(u >> 16);
    lo = (unsigned short)(ul >> 16);
}

// ---------------- CSR build (by dst) ----------------
__global__ void hist_kernel(const int* __restrict__ dst, int* __restrict__ deg, int E) {
    int e = blockIdx.x * blockDim.x + threadIdx.x;
    if (e < E) atomicAdd(&deg[dst[e]], 1);
}

__global__ __launch_bounds__(256) void scan_partial_kernel(
    const int* __restrict__ deg, int* __restrict__ blocksum, int N) {
    __shared__ int red[256];
    int t = threadIdx.x;
    int base = blockIdx.x * SCAN_CHUNK;
    int s = 0;
#pragma unroll
    for (int i = 0; i < 8; ++i) {
        int idx = base + i * 256 + t;
        if (idx < N) s += deg[idx];
    }
    red[t] = s;
    __syncthreads();
    for (int off = 128; off > 0; off >>= 1) {
        if (t < off) red[t] += red[t + off];
        __syncthreads();
    }
    if (t == 0) blocksum[blockIdx.x] = red[0];
}

__global__ void scan_sums_kernel(int* __restrict__ blocksum, int PB,
                                 int* __restrict__ rowptr, int N, int E) {
    if (threadIdx.x == 0) {
        int run = 0;
        for (int i = 0; i < PB; ++i) {
            int v = blocksum[i];
            blocksum[i] = run;
            run += v;
        }
        rowptr[N] = E;
    }
}

__global__ __launch_bounds__(256) void scan_fill_kernel(
    const int* __restrict__ deg, const int* __restrict__ blocksum,
    int* __restrict__ rowptr, int* __restrict__ cursor, int N) {
    __shared__ int tsum[256];
    int t = threadIdx.x;
    int base = blockIdx.x * SCAN_CHUNK + t * 8;
    int local[8];
    int s = 0;
#pragma unroll
    for (int i = 0; i < 8; ++i) {
        int idx = base + i;
        local[i] = (idx < N) ? deg[idx] : 0;
        s += local[i];
    }
    tsum[t] = s;
    __syncthreads();
    for (int off = 1; off < 256; off <<= 1) {
        int v = (t >= off) ? tsum[t - off] : 0;
        __syncthreads();
        tsum[t] += v;
        __syncthreads();
    }
    int prefix = blocksum[blockIdx.x] + ((t == 0) ? 0 : tsum[t - 1]);
#pragma unroll
    for (int i = 0; i < 8; ++i) {
        int idx = base + i;
        if (idx < N) {
            rowptr[idx] = prefix;
            cursor[idx] = prefix;
            prefix += local[i];
        }
    }
}

__global__ void fill_kernel(const int* __restrict__ src, const int* __restrict__ dst,
                            int* __restrict__ cursor, int* __restrict__ col, int E) {
    int e = blockIdx.x * blockDim.x + threadIdx.x;
    if (e < E) {
        int pos = atomicAdd(&cursor[dst[e]], 1);
        col[pos] = src[e];
    }
}

// ---------------- GIN aggregation: writes bf16 hi/lo split directly ----------------
__global__ __launch_bounds__(256) void aggregate_kernel(
    const float* __restrict__ h, const int* __restrict__ rowptr,
    const int* __restrict__ col, unsigned short* __restrict__ outh,
    unsigned short* __restrict__ outl, int N) {
    int node = blockIdx.x * 8 + (threadIdx.x >> 5);
    int q = threadIdx.x & 31;
    if (node >= N) return;
    const float4* h4 = (const float4*)h;
    int e0 = rowptr[node], e1 = rowptr[node + 1];
    float4 acc = h4[(size_t)node * 32 + q];
    int e = e0;
    for (; e + 1 < e1; e += 2) {
        int j0 = col[e], j1 = col[e + 1];
        float4 v0 = h4[(size_t)j0 * 32 + q];
        float4 v1 = h4[(size_t)j1 * 32 + q];
        acc.x += v0.x + v1.x;
        acc.y += v0.y + v1.y;
        acc.z += v0.z + v1.z;
        acc.w += v0.w + v1.w;
    }
    if (e < e1) {
        float4 v = h4[(size_t)col[e] * 32 + q];
        acc.x += v.x; acc.y += v.y; acc.z += v.z; acc.w += v.w;
    }
    ushort4 hh, ll;
    split_bf16(acc.x, hh.x, ll.x);
    split_bf16(acc.y, hh.y, ll.y);
    split_bf16(acc.z, hh.z, ll.z);
    split_bf16(acc.w, hh.w, ll.w);
    *(ushort4*)&outh[(size_t)node * D + q * 4] = hh;
    *(ushort4*)&outl[(size_t)node * D + q * 4] = ll;
}

// ---------------- W prep: transpose + split into bf16 hi/lo, layout [n][k] ----------------
__global__ void wprep_kernel(const float* __restrict__ W1, const float* __restrict__ W2,
                             unsigned short* __restrict__ Wth, unsigned short* __restrict__ Wtl,
                             int total) {
    int idx = blockIdx.x * 256 + threadIdx.x;
    if (idx >= total) return;
    int mat = idx >> 14;             // l*2 + which
    int rem = idx & 16383;
    int n = rem >> 7, k = rem & 127;
    int l = mat >> 1;
    const float* W = (mat & 1) ? W2 : W1;
    float v = W[(size_t)l * D * D + k * D + n];
    unsigned short h, lo;
    split_bf16(v, h, lo);
    Wth[idx] = h;
    Wtl[idx] = lo;
}

// ---------------- MFMA GEMM (split-bf16, 3 terms): out = [elu?](A @ W + bias)
// A: BNSTAGE ? elu(Z*scale+shift) : (Ah+Al)  — 64 rows x 128 k per block
// W: Wth/Wtl [n][k] bf16. STATS: accumulate col sum/sumsq of output into colsum.
template <bool BNSTAGE, bool ELU_OUT, bool STATS>
__global__ __launch_bounds__(256, 3) void gemm_mfma(
    const unsigned short* __restrict__ Ah, const unsigned short* __restrict__ Al,
    const float* __restrict__ Z,
    const unsigned short* __restrict__ Wth, const unsigned short* __restrict__ Wtl,
    const float* __restrict__ bias,
    const float* __restrict__ scale, const float* __restrict__ shift,
    float* __restrict__ outp, float* __restrict__ colsum, int N) {
    __shared__ unsigned short sAh[64 * 136];
    __shared__ unsigned short sAl[64 * 136];
    __shared__ float bnsum[2 * D];
    const int tid = threadIdx.x;
    const int row0 = blockIdx.x * 64;

    if (STATS && tid < 2 * D) bnsum[tid] = 0.f;

    if (BNSTAGE) {
#pragma unroll
        for (int it = 0; it < 8; ++it) {
            int idx = tid + it * 256;
            int r = idx >> 5;         // 0..63
            int c4 = idx & 31;        // float4 column group
            int gr = row0 + r;
            float4 v = make_float4(0.f, 0.f, 0.f, 0.f);
            if (gr < N) v = *(const float4*)&Z[(size_t)gr * D + c4 * 4];
            float4 sc = *(const float4*)&scale[c4 * 4];
            float4 sh = *(const float4*)&shift[c4 * 4];
            float e0 = elu_f(v.x * sc.x + sh.x);
            float e1 = elu_f(v.y * sc.y + sh.y);
            float e2 = elu_f(v.z * sc.z + sh.z);
            float e3 = elu_f(v.w * sc.w + sh.w);
            ushort4 hh, ll;
            split_bf16(e0, hh.x, ll.x);
            split_bf16(e1, hh.y, ll.y);
            split_bf16(e2, hh.z, ll.z);
            split_bf16(e3, hh.w, ll.w);
            *(ushort4*)&sAh[r * 136 + c4 * 4] = hh;
            *(ushort4*)&sAl[r * 136 + c4 * 4] = ll;
        }
    } else {
#pragma unroll
        for (int it = 0; it < 4; ++it) {
            int idx = tid + it * 256;
            int r = idx >> 4;          // 0..63
            int k8 = (idx & 15) * 8;   // 0..120
            int gr = row0 + r;
            uint4 va = make_uint4(0u, 0u, 0u, 0u), vb = make_uint4(0u, 0u, 0u, 0u);
            if (gr < N) {
                va = *(const uint4*)&Ah[(size_t)gr * D + k8];
                vb = *(const uint4*)&Al[(size_t)gr * D + k8];
            }
            *(uint4*)&sAh[r * 136 + k8] = va;
            *(uint4*)&sAl[r * 136 + k8] = vb;
        }
    }
    __syncthreads();

    const int wave = tid >> 6, lane = tid & 63;
    const int wm = wave >> 1, wn = wave & 1;
    const int l15 = lane & 15, quad = lane >> 4;

    floatx4 acc[2][4];
#pragma unroll
    for (int mt = 0; mt < 2; ++mt)
#pragma unroll
        for (int nt = 0; nt < 4; ++nt)
            acc[mt][nt] = (floatx4){0.f, 0.f, 0.f, 0.f};

#pragma unroll
    for (int ks = 0; ks < 4; ++ks) {
        const int kf = ks * 32 + quad * 8;
        short8 bh[4], bl[4];
#pragma unroll
        for (int nt = 0; nt < 4; ++nt) {
            int n = wn * 64 + nt * 16 + l15;
            bh[nt] = *(const short8*)&Wth[n * D + kf];
            bl[nt] = *(const short8*)&Wtl[n * D + kf];
        }
        short8 ah[2], al[2];
#pragma unroll
        for (int mt = 0; mt < 2; ++mt) {
            int off = (wm * 32 + mt * 16 + l15) * 136 + kf;
            ah[mt] = *(const short8*)&sAh[off];
            al[mt] = *(const short8*)&sAl[off];
        }
#pragma unroll
        for (int mt = 0; mt < 2; ++mt)
#pragma unroll
            for (int nt = 0; nt < 4; ++nt) {
                acc[mt][nt] = __builtin_amdgcn_mfma_f32_16x16x32_bf16(ah[mt], bh[nt], acc[mt][nt], 0, 0, 0);
                acc[mt][nt] = __builtin_amdgcn_mfma_f32_16x16x32_bf16(ah[mt], bl[nt], acc[mt][nt], 0, 0, 0);
                acc[mt][nt] = __builtin_amdgcn_mfma_f32_16x16x32_bf16(al[mt], bh[nt], acc[mt][nt], 0, 0, 0);
            }
    }

#pragma unroll
    for (int nt = 0; nt < 4; ++nt) {
        int c = wn * 64 + nt * 16 + l15;
        float b = bias[c];
        float s = 0.f, s2 = 0.f;
#pragma unroll
        for (int mt = 0; mt < 2; ++mt) {
#pragma unroll
            for (int r = 0; r < 4; ++r) {
                int gm = row0 + wm * 32 + mt * 16 + quad * 4 + r;
                float v = acc[mt][nt][r] + b;
                if (ELU_OUT) v = elu_f(v);
                if (gm < N) {
                    outp[(size_t)gm * D + c] = v;
                    if (STATS) { s += v; s2 += v * v; }
                }
            }
        }
        if (STATS) {
            atomicAdd(&bnsum[c], s);
            atomicAdd(&bnsum[D + c], s2);
        }
    }
    if (STATS) {
        __syncthreads();
        if (tid < D) {
            atomicAdd(&colsum[tid], bnsum[tid]);
            atomicAdd(&colsum[D + tid], bnsum[D + tid]);
        }
    }
}

__global__ void bn_finalize_kernel(const float* __restrict__ sums,
                                   const float* __restrict__ gamma,
                                   const float* __restrict__ beta,
                                   float* __restrict__ scale, float* __restrict__ shift,
                                   int N) {
    int c = threadIdx.x;
    float invN = 1.0f / (float)N;
    float mu = sums[c] * invN;
    float var = sums[D + c] * invN - mu * mu;
    float rs = rsqrtf(var + 1e-5f);
    float sc = gamma[c] * rs;
    scale[c] = sc;
    shift[c] = beta[c] - mu * sc;
}

// ---------------- global mean pool ----------------
__global__ __launch_bounds__(128) void pool_kernel(
    const float* __restrict__ h, const int* __restrict__ batch,
    float* __restrict__ pooled, float* __restrict__ cnt, int N) {
    int c = threadIdx.x;
    int r0 = blockIdx.x * 256;
    if (r0 >= N) return;
    int rend = r0 + 256; if (rend > N) rend = N;
    int cur = batch[r0];
    float acc = 0.f;
    float cacc = 0.f;
    for (int r = r0; r < rend; ++r) {
        int b = batch[r];
        if (b != cur) {
            atomicAdd(&pooled[(size_t)cur * D + c], acc);
            if (c == 0) atomicAdd(&cnt[cur], cacc);
            acc = 0.f; cacc = 0.f; cur = b;
        }
        acc += h[(size_t)r * D + c];
        cacc += 1.f;
    }
    atomicAdd(&pooled[(size_t)cur * D + c], acc);
    if (c == 0) atomicAdd(&cnt[cur], cacc);
}

__global__ void final_linear_kernel(const float* __restrict__ pooled,
                                    const float* __restrict__ cnt,
                                    const float* __restrict__ linW,
                                    const float* __restrict__ linb,
                                    float* __restrict__ out, int G) {
    int t = blockIdx.x * blockDim.x + threadIdx.x;
    if (t >= G * 2) return;
    int g = t >> 1, o = t & 1;
    float inv = 1.0f / fmaxf(cnt[g], 1.0f);
    float s = linb[o];
    for (int c = 0; c < D; ++c)
        s += pooled[(size_t)g * D + c] * inv * linW[c * 2 + o];
    out[t] = s;
}

extern "C" void kernel_launch(void* const* d_in, const int* in_sizes, int n_in,
                              void* d_out, int out_size, void* d_ws, size_t ws_size,
                              hipStream_t stream) {
    const float* x      = (const float*)d_in[0];
    const int*  eidx    = (const int*)d_in[1];
    const int*  batch   = (const int*)d_in[2];
    const float* W1     = (const float*)d_in[3];
    const float* b1     = (const float*)d_in[4];
    const float* gamma  = (const float*)d_in[5];
    const float* beta   = (const float*)d_in[6];
    const float* W2     = (const float*)d_in[7];
    const float* b2     = (const float*)d_in[8];
    const float* linW   = (const float*)d_in[9];
    const float* linb   = (const float*)d_in[10];
    float* out = (float*)d_out;

    const int N = in_sizes[0] / D;
    const int E = in_sizes[1] / 2;
    const int L = in_sizes[3] / (D * D);
    const int G = out_size / 2;
    const int* esrc = eidx;
    const int* edst = eidx + E;

    size_t off = 0;
    auto carve = [&](size_t bytes) -> void* {
        void* p = (char*)d_ws + off;
        off += (bytes + 255) & ~(size_t)255;
        return p;
    };
    const size_t ND = (size_t)N * D;
    const int PB = (N + SCAN_CHUNK - 1) / SCAN_CHUNK;
    const int WTOT = 2 * L * D * D;
    unsigned short* aggh = (unsigned short*)carve(ND * 2);
    unsigned short* aggl = (unsigned short*)carve(ND * 2);
    float* z1     = (float*)carve(ND * 4);
    float* hbuf   = (float*)carve(ND * 4);
    unsigned short* Wth = (unsigned short*)carve((size_t)WTOT * 2);
    unsigned short* Wtl = (unsigned short*)carve((size_t)WTOT * 2);
    int* deg      = (int*)carve((size_t)N * 4);
    int* rowptr   = (int*)carve((size_t)(N + 1) * 4);
    int* cursor   = (int*)carve((size_t)N * 4);
    int* col      = (int*)carve((size_t)E * 4);
    int* blocksum = (int*)carve((size_t)PB * 4);
    float* colsum = (float*)carve(2 * D * 4);
    float* scale  = (float*)carve(D * 4);
    float* shift  = (float*)carve(D * 4);
    float* pooled = (float*)carve((size_t)G * D * 4);
    float* cnt    = (float*)carve((size_t)G * 4);
    (void)ws_size; (void)n_in;

    // ---- CSR build + W prep ----
    hipMemsetAsync(deg, 0, (size_t)N * 4, stream);
    hist_kernel<<<(E + 255) / 256, 256, 0, stream>>>(edst, deg, E);
    wprep_kernel<<<(WTOT + 255) / 256, 256, 0, stream>>>(W1, W2, Wth, Wtl, WTOT);
    scan_partial_kernel<<<PB, 256, 0, stream>>>(deg, blocksum, N);
    scan_sums_kernel<<<1, 64, 0, stream>>>(blocksum, PB, rowptr, N, E);
    scan_fill_kernel<<<PB, 256, 0, stream>>>(deg, blocksum, rowptr, cursor, N);
    fill_kernel<<<(E + 255) / 256, 256, 0, stream>>>(esrc, edst, cursor, col, E);

    const int gemm_grid = (N + 63) / 64;
    const int agg_grid = (N + 7) / 8;
    const float* hin = x;
    for (int l = 0; l < L; ++l) {
        aggregate_kernel<<<agg_grid, 256, 0, stream>>>(hin, rowptr, col, aggh, aggl, N);
        hipMemsetAsync(colsum, 0, 2 * D * 4, stream);
        gemm_mfma<false, false, true><<<gemm_grid, 256, 0, stream>>>(
            aggh, aggl, nullptr,
            Wth + (size_t)(l * 2) * D * D, Wtl + (size_t)(l * 2) * D * D,
            b1 + (size_t)l * D, nullptr, nullptr, z1, colsum, N);
        bn_finalize_kernel<<<1, D, 0, stream>>>(colsum, gamma + (size_t)l * D,
                                                beta + (size_t)l * D, scale, shift, N);
        gemm_mfma<true, true, false><<<gemm_grid, 256, 0, stream>>>(
            nullptr, nullptr, z1,
            Wth + (size_t)(l * 2 + 1) * D * D, Wtl + (size_t)(l * 2 + 1) * D * D,
            b2 + (size_t)l * D, scale, shift, hbuf, nullptr, N);
        hin = hbuf;
    }

    hipMemsetAsync(pooled, 0, (size_t)G * D * 4, stream);
    hipMemsetAsync(cnt, 0, (size_t)G * 4, stream);
    pool_kernel<<<(N + 255) / 256, 128, 0, stream>>>(hbuf, batch, pooled, cnt, N);
    final_linear_kernel<<<(G * 2 + 255) / 256, 256, 0, stream>>>(pooled, cnt, linW, linb, out, G);
}

// Round 4
// 1179.545 us; speedup vs baseline: 1.4781x; 1.1349x over previous
//
#include <hip/hip_runtime.h>
#include <cstdint>

#define D 128
#define BKT_SHIFT 8
#define EDGES_PER_BLOCK 4096

typedef __attribute__((ext_vector_type(8))) short short8;
typedef __attribute__((ext_vector_type(4))) float floatx4;

__device__ __forceinline__ float elu_f(float x) {
    return x > 0.0f ? x : __expf(x) - 1.0f;
}

// truncation split: a = hi + lo + O(2^-16 |a|), hi/lo bf16 bit patterns
__device__ __forceinline__ void split_bf16(float a, unsigned short& hi, unsigned short& lo) {
    unsigned u = __builtin_bit_cast(unsigned, a);
    unsigned hb = u & 0xffff0000u;
    float hf = __builtin_bit_cast(float, hb);
    float rl = a - hf;                       // exact
    unsigned ul = __builtin_bit_cast(unsigned, rl);
    hi = (unsigned short)(u >> 16);
    lo = (unsigned short)(ul >> 16);
}

// ================= bucketed CSR build =================
// Level 1: per-block LDS histogram of dst>>8
__global__ __launch_bounds__(256) void bucket_count_kernel(
    const int* __restrict__ dst, int* __restrict__ bcnt, int E, int NB) {
    __shared__ int lcnt[512];
    int t = threadIdx.x;
    lcnt[t] = 0; lcnt[t + 256] = 0;
    __syncthreads();
    int base = blockIdx.x * EDGES_PER_BLOCK;
#pragma unroll
    for (int i = 0; i < 16; ++i) {
        int idx = base + i * 256 + t;
        if (idx < E) atomicAdd(&lcnt[dst[idx] >> BKT_SHIFT], 1);
    }
    __syncthreads();
    for (int b = t; b < NB; b += 256) {
        int c = lcnt[b];
        if (c) atomicAdd(&bcnt[b], c);
    }
}

// scan bucket counts -> bucketoff / gcursor; also rowptr[N]=E
__global__ __launch_bounds__(512) void scan_buckets_kernel(
    const int* __restrict__ bcnt, int* __restrict__ bucketoff,
    int* __restrict__ gcursor, int NB, int E, int* __restrict__ rowptr, int N) {
    __shared__ int s[512];
    int t = threadIdx.x;
    s[t] = (t < NB) ? bcnt[t] : 0;
    __syncthreads();
    for (int off = 1; off < 512; off <<= 1) {
        int v = (t >= off) ? s[t - off] : 0;
        __syncthreads();
        s[t] += v;
        __syncthreads();
    }
    int excl = (t == 0) ? 0 : s[t - 1];
    if (t < NB) { bucketoff[t] = excl; gcursor[t] = excl; }
    if (t == 0) { bucketoff[NB] = E; rowptr[N] = E; }
}

// Level 1 scatter: multisplit (src,dst) pairs into bucket-grouped staging
__global__ __launch_bounds__(256) void bucket_scatter_kernel(
    const int* __restrict__ src, const int* __restrict__ dst,
    int* __restrict__ gcursor, int2* __restrict__ staging, int E, int NB) {
    __shared__ int lcnt[512];
    __shared__ int lbase[512];
    int t = threadIdx.x;
    lcnt[t] = 0; lcnt[t + 256] = 0;
    __syncthreads();
    int base = blockIdx.x * EDGES_PER_BLOCK;
    int s_[16], d_[16], r_[16];
#pragma unroll
    for (int i = 0; i < 16; ++i) {
        int idx = base + i * 256 + t;
        if (idx < E) {
            s_[i] = src[idx];
            d_[i] = dst[idx];
            r_[i] = atomicAdd(&lcnt[d_[i] >> BKT_SHIFT], 1);
        }
    }
    __syncthreads();
    for (int b = t; b < NB; b += 256) {
        int c = lcnt[b];
        if (c) lbase[b] = atomicAdd(&gcursor[b], c);
    }
    __syncthreads();
#pragma unroll
    for (int i = 0; i < 16; ++i) {
        int idx = base + i * 256 + t;
        if (idx < E) {
            int bkt = d_[i] >> BKT_SHIFT;
            staging[lbase[bkt] + r_[i]] = make_int2(s_[i], d_[i]);
        }
    }
}

// Level 2: one block per bucket -> rowptr slice + col slice (single-CU locality)
__global__ __launch_bounds__(256) void bucket_build_kernel(
    const int2* __restrict__ staging, const int* __restrict__ bucketoff,
    int* __restrict__ rowptr, int* __restrict__ col, int N) {
    __shared__ int hcnt[256];
    __shared__ int hoff[256];
    int t = threadIdx.x;
    int node0 = blockIdx.x << BKT_SHIFT;
    int off0 = bucketoff[blockIdx.x], off1 = bucketoff[blockIdx.x + 1];
    hcnt[t] = 0;
    __syncthreads();
    for (int i = off0 + t; i < off1; i += 256)
        atomicAdd(&hcnt[staging[i].y - node0], 1);
    __syncthreads();
    hoff[t] = hcnt[t];
    __syncthreads();
    for (int off = 1; off < 256; off <<= 1) {
        int u = (t >= off) ? hoff[t - off] : 0;
        __syncthreads();
        hoff[t] += u;
        __syncthreads();
    }
    int myoff = (t == 0) ? 0 : hoff[t - 1];   // exclusive scan
    __syncthreads();
    hoff[t] = myoff;
    hcnt[t] = 0;
    if (node0 + t < N) rowptr[node0 + t] = off0 + myoff;
    __syncthreads();
    for (int i = off0 + t; i < off1; i += 256) {
        int2 p = staging[i];
        int dl = p.y - node0;
        int pos = off0 + hoff[dl] + atomicAdd(&hcnt[dl], 1);
        col[pos] = p.x;
    }
}

// ---------------- GIN aggregation: writes bf16 hi/lo split directly ----------------
__global__ __launch_bounds__(256) void aggregate_kernel(
    const float* __restrict__ h, const int* __restrict__ rowptr,
    const int* __restrict__ col, unsigned short* __restrict__ outh,
    unsigned short* __restrict__ outl, int N) {
    int node = blockIdx.x * 8 + (threadIdx.x >> 5);
    int q = threadIdx.x & 31;
    if (node >= N) return;
    const float4* h4 = (const float4*)h;
    int e0 = rowptr[node], e1 = rowptr[node + 1];
    float4 acc = h4[(size_t)node * 32 + q];
    int e = e0;
    for (; e + 3 < e1; e += 4) {
        int j0 = col[e], j1 = col[e + 1], j2 = col[e + 2], j3 = col[e + 3];
        float4 v0 = h4[(size_t)j0 * 32 + q];
        float4 v1 = h4[(size_t)j1 * 32 + q];
        float4 v2 = h4[(size_t)j2 * 32 + q];
        float4 v3 = h4[(size_t)j3 * 32 + q];
        acc.x += (v0.x + v1.x) + (v2.x + v3.x);
        acc.y += (v0.y + v1.y) + (v2.y + v3.y);
        acc.z += (v0.z + v1.z) + (v2.z + v3.z);
        acc.w += (v0.w + v1.w) + (v2.w + v3.w);
    }
    for (; e < e1; ++e) {
        float4 v = h4[(size_t)col[e] * 32 + q];
        acc.x += v.x; acc.y += v.y; acc.z += v.z; acc.w += v.w;
    }
    ushort4 hh, ll;
    split_bf16(acc.x, hh.x, ll.x);
    split_bf16(acc.y, hh.y, ll.y);
    split_bf16(acc.z, hh.z, ll.z);
    split_bf16(acc.w, hh.w, ll.w);
    *(ushort4*)&outh[(size_t)node * D + q * 4] = hh;
    *(ushort4*)&outl[(size_t)node * D + q * 4] = ll;
}

// ---------------- W prep: transpose + split into bf16 hi/lo, layout [n][k] ----------------
__global__ void wprep_kernel(const float* __restrict__ W1, const float* __restrict__ W2,
                             unsigned short* __restrict__ Wth, unsigned short* __restrict__ Wtl,
                             int total) {
    int idx = blockIdx.x * 256 + threadIdx.x;
    if (idx >= total) return;
    int mat = idx >> 14;
    int rem = idx & 16383;
    int n = rem >> 7, k = rem & 127;
    int l = mat >> 1;
    const float* W = (mat & 1) ? W2 : W1;
    float v = W[(size_t)l * D * D + k * D + n];
    unsigned short h, lo;
    split_bf16(v, h, lo);
    Wth[idx] = h;
    Wtl[idx] = lo;
}

// ---------------- MFMA GEMM (split-bf16, 3 terms): out = [elu?](A @ W + bias)
// BNSTAGE: A = elu(Z*scale+shift), scale/shift computed in-block from colsum_in
// STATS: accumulate col sum/sumsq of output into colsum_out
template <bool BNSTAGE, bool ELU_OUT, bool STATS>
__global__ __launch_bounds__(256, 3) void gemm_mfma(
    const unsigned short* __restrict__ Ah, const unsigned short* __restrict__ Al,
    const float* __restrict__ Z,
    const unsigned short* __restrict__ Wth, const unsigned short* __restrict__ Wtl,
    const float* __restrict__ bias,
    const float* __restrict__ colsum_in, const float* __restrict__ gamma,
    const float* __restrict__ beta,
    float* __restrict__ outp, float* __restrict__ colsum_out, int N) {
    __shared__ unsigned short sAh[64 * 136];
    __shared__ unsigned short sAl[64 * 136];
    __shared__ float bnsum[2 * D];
    __shared__ float s_sc[D];
    __shared__ float s_sh[D];
    const int tid = threadIdx.x;
    const int row0 = blockIdx.x * 64;

    if (STATS && tid < 2 * D) bnsum[tid] = 0.f;

    if (BNSTAGE) {
        if (tid < D) {
            float invN = 1.0f / (float)N;
            float mu = colsum_in[tid] * invN;
            float var = colsum_in[D + tid] * invN - mu * mu;
            float rs = rsqrtf(var + 1e-5f);
            float sc = gamma[tid] * rs;
            s_sc[tid] = sc;
            s_sh[tid] = beta[tid] - mu * sc;
        }
        __syncthreads();
#pragma unroll
        for (int it = 0; it < 8; ++it) {
            int idx = tid + it * 256;
            int r = idx >> 5;
            int c4 = idx & 31;
            int gr = row0 + r;
            float4 v = make_float4(0.f, 0.f, 0.f, 0.f);
            if (gr < N) v = *(const float4*)&Z[(size_t)gr * D + c4 * 4];
            float4 sc = *(const float4*)&s_sc[c4 * 4];
            float4 sh = *(const float4*)&s_sh[c4 * 4];
            float e0 = elu_f(v.x * sc.x + sh.x);
            float e1 = elu_f(v.y * sc.y + sh.y);
            float e2 = elu_f(v.z * sc.z + sh.z);
            float e3 = elu_f(v.w * sc.w + sh.w);
            ushort4 hh, ll;
            split_bf16(e0, hh.x, ll.x);
            split_bf16(e1, hh.y, ll.y);
            split_bf16(e2, hh.z, ll.z);
            split_bf16(e3, hh.w, ll.w);
            *(ushort4*)&sAh[r * 136 + c4 * 4] = hh;
            *(ushort4*)&sAl[r * 136 + c4 * 4] = ll;
        }
    } else {
#pragma unroll
        for (int it = 0; it < 4; ++it) {
            int idx = tid + it * 256;
            int r = idx >> 4;
            int k8 = (idx & 15) * 8;
            int gr = row0 + r;
            uint4 va = make_uint4(0u, 0u, 0u, 0u), vb = make_uint4(0u, 0u, 0u, 0u);
            if (gr < N) {
                va = *(const uint4*)&Ah[(size_t)gr * D + k8];
                vb = *(const uint4*)&Al[(size_t)gr * D + k8];
            }
            *(uint4*)&sAh[r * 136 + k8] = va;
            *(uint4*)&sAl[r * 136 + k8] = vb;
        }
    }
    __syncthreads();

    const int wave = tid >> 6, lane = tid & 63;
    const int wm = wave >> 1, wn = wave & 1;
    const int l15 = lane & 15, quad = lane >> 4;

    floatx4 acc[2][4];
#pragma unroll
    for (int mt = 0; mt < 2; ++mt)
#pragma unroll
        for (int nt = 0; nt < 4; ++nt)
            acc[mt][nt] = (floatx4){0.f, 0.f, 0.f, 0.f};

#pragma unroll
    for (int ks = 0; ks < 4; ++ks) {
        const int kf = ks * 32 + quad * 8;
        short8 bh[4], bl[4];
#pragma unroll
        for (int nt = 0; nt < 4; ++nt) {
            int n = wn * 64 + nt * 16 + l15;
            bh[nt] = *(const short8*)&Wth[n * D + kf];
            bl[nt] = *(const short8*)&Wtl[n * D + kf];
        }
        short8 ah[2], al[2];
#pragma unroll
        for (int mt = 0; mt < 2; ++mt) {
            int off = (wm * 32 + mt * 16 + l15) * 136 + kf;
            ah[mt] = *(const short8*)&sAh[off];
            al[mt] = *(const short8*)&sAl[off];
        }
#pragma unroll
        for (int mt = 0; mt < 2; ++mt)
#pragma unroll
            for (int nt = 0; nt < 4; ++nt) {
                acc[mt][nt] = __builtin_amdgcn_mfma_f32_16x16x32_bf16(ah[mt], bh[nt], acc[mt][nt], 0, 0, 0);
                acc[mt][nt] = __builtin_amdgcn_mfma_f32_16x16x32_bf16(ah[mt], bl[nt], acc[mt][nt], 0, 0, 0);
                acc[mt][nt] = __builtin_amdgcn_mfma_f32_16x16x32_bf16(al[mt], bh[nt], acc[mt][nt], 0, 0, 0);
            }
    }

#pragma unroll
    for (int nt = 0; nt < 4; ++nt) {
        int c = wn * 64 + nt * 16 + l15;
        float b = bias[c];
        float s = 0.f, s2 = 0.f;
#pragma unroll
        for (int mt = 0; mt < 2; ++mt) {
#pragma unroll
            for (int r = 0; r < 4; ++r) {
                int gm = row0 + wm * 32 + mt * 16 + quad * 4 + r;
                float v = acc[mt][nt][r] + b;
                if (ELU_OUT) v = elu_f(v);
                if (gm < N) {
                    outp[(size_t)gm * D + c] = v;
                    if (STATS) { s += v; s2 += v * v; }
                }
            }
        }
        if (STATS) {
            atomicAdd(&bnsum[c], s);
            atomicAdd(&bnsum[D + c], s2);
        }
    }
    if (STATS) {
        __syncthreads();
        if (tid < D) {
            atomicAdd(&colsum_out[tid], bnsum[tid]);
            atomicAdd(&colsum_out[D + tid], bnsum[D + tid]);
        }
    }
}

// ---------------- global mean pool ----------------
__global__ __launch_bounds__(128) void pool_kernel(
    const float* __restrict__ h, const int* __restrict__ batch,
    float* __restrict__ pooled, float* __restrict__ cnt, int N) {
    int c = threadIdx.x;
    int r0 = blockIdx.x * 256;
    if (r0 >= N) return;
    int rend = r0 + 256; if (rend > N) rend = N;
    int cur = batch[r0];
    float acc = 0.f;
    float cacc = 0.f;
    for (int r = r0; r < rend; ++r) {
        int b = batch[r];
        if (b != cur) {
            atomicAdd(&pooled[(size_t)cur * D + c], acc);
            if (c == 0) atomicAdd(&cnt[cur], cacc);
            acc = 0.f; cacc = 0.f; cur = b;
        }
        acc += h[(size_t)r * D + c];
        cacc += 1.f;
    }
    atomicAdd(&pooled[(size_t)cur * D + c], acc);
    if (c == 0) atomicAdd(&cnt[cur], cacc);
}

__global__ void final_linear_kernel(const float* __restrict__ pooled,
                                    const float* __restrict__ cnt,
                                    const float* __restrict__ linW,
                                    const float* __restrict__ linb,
                                    float* __restrict__ out, int G) {
    int t = blockIdx.x * blockDim.x + threadIdx.x;
    if (t >= G * 2) return;
    int g = t >> 1, o = t & 1;
    float inv = 1.0f / fmaxf(cnt[g], 1.0f);
    float s = linb[o];
    for (int c = 0; c < D; ++c)
        s += pooled[(size_t)g * D + c] * inv * linW[c * 2 + o];
    out[t] = s;
}

extern "C" void kernel_launch(void* const* d_in, const int* in_sizes, int n_in,
                              void* d_out, int out_size, void* d_ws, size_t ws_size,
                              hipStream_t stream) {
    const float* x      = (const float*)d_in[0];
    const int*  eidx    = (const int*)d_in[1];
    const int*  batch   = (const int*)d_in[2];
    const float* W1     = (const float*)d_in[3];
    const float* b1     = (const float*)d_in[4];
    const float* gamma  = (const float*)d_in[5];
    const float* beta   = (const float*)d_in[6];
    const float* W2     = (const float*)d_in[7];
    const float* b2     = (const float*)d_in[8];
    const float* linW   = (const float*)d_in[9];
    const float* linb   = (const float*)d_in[10];
    float* out = (float*)d_out;

    const int N = in_sizes[0] / D;
    const int E = in_sizes[1] / 2;
    const int L = in_sizes[3] / (D * D);
    const int G = out_size / 2;
    const int* esrc = eidx;
    const int* edst = eidx + E;
    const int NB = (N + 255) >> 8;

    size_t off = 0;
    auto carve = [&](size_t bytes) -> void* {
        void* p = (char*)d_ws + off;
        off += (bytes + 255) & ~(size_t)255;
        return p;
    };
    const size_t ND = (size_t)N * D;
    const int WTOT = 2 * L * D * D;
    unsigned short* aggh = (unsigned short*)carve(ND * 2);
    unsigned short* aggl = (unsigned short*)carve(ND * 2);
    float* z1     = (float*)carve(ND * 4);           // also aliased as CSR staging
    float* hbuf   = (float*)carve(ND * 4);
    unsigned short* Wth = (unsigned short*)carve((size_t)WTOT * 2);
    unsigned short* Wtl = (unsigned short*)carve((size_t)WTOT * 2);
    int* rowptr   = (int*)carve((size_t)(N + 1) * 4);
    int* col      = (int*)carve((size_t)E * 4);
    int* bcnt     = (int*)carve(512 * 4);            // contiguous with colsum4 for one memset
    float* colsum4 = (float*)carve((size_t)4 * 2 * D * 4);
    int* bucketoff = (int*)carve(513 * 4);
    int* gcursor  = (int*)carve(512 * 4);
    float* pooled = (float*)carve((size_t)G * D * 4); // contiguous with cnt
    float* cnt    = (float*)carve((size_t)G * 4);
    int2* staging = (int2*)z1;                        // CSR build finishes before z1 used
    (void)ws_size; (void)n_in;

    // ---- zero accumulators (2 memsets total) ----
    hipMemsetAsync(bcnt, 0, 512 * 4 + (size_t)4 * 2 * D * 4, stream);
    hipMemsetAsync(pooled, 0, (size_t)G * D * 4 + 256, stream);

    // ---- bucketed CSR build ----
    const int EB = (E + EDGES_PER_BLOCK - 1) / EDGES_PER_BLOCK;
    bucket_count_kernel<<<EB, 256, 0, stream>>>(edst, bcnt, E, NB);
    scan_buckets_kernel<<<1, 512, 0, stream>>>(bcnt, bucketoff, gcursor, NB, E, rowptr, N);
    bucket_scatter_kernel<<<EB, 256, 0, stream>>>(esrc, edst, gcursor, staging, E, NB);
    bucket_build_kernel<<<NB, 256, 0, stream>>>(staging, bucketoff, rowptr, col, N);
    wprep_kernel<<<(WTOT + 255) / 256, 256, 0, stream>>>(W1, W2, Wth, Wtl, WTOT);

    const int gemm_grid = (N + 63) / 64;
    const int agg_grid = (N + 7) / 8;
    const float* hin = x;
    for (int l = 0; l < L; ++l) {
        float* colsum = colsum4 + (size_t)l * 2 * D;
        aggregate_kernel<<<agg_grid, 256, 0, stream>>>(hin, rowptr, col, aggh, aggl, N);
        gemm_mfma<false, false, true><<<gemm_grid, 256, 0, stream>>>(
            aggh, aggl, nullptr,
            Wth + (size_t)(l * 2) * D * D, Wtl + (size_t)(l * 2) * D * D,
            b1 + (size_t)l * D, nullptr, nullptr, nullptr, z1, colsum, N);
        gemm_mfma<true, true, false><<<gemm_grid, 256, 0, stream>>>(
            nullptr, nullptr, z1,
            Wth + (size_t)(l * 2 + 1) * D * D, Wtl + (size_t)(l * 2 + 1) * D * D,
            b2 + (size_t)l * D, colsum, gamma + (size_t)l * D, beta + (size_t)l * D,
            hbuf, nullptr, N);
        hin = hbuf;
    }

    pool_kernel<<<(N + 255) / 256, 128, 0, stream>>>(hbuf, batch, pooled, cnt, N);
    final_linear_kernel<<<(G * 2 + 255) / 256, 256, 0, stream>>>(pooled, cnt, linW, linb, out, G);
}

// Round 5
// 1079.322 us; speedup vs baseline: 1.6153x; 1.0929x over previous
//
#include <hip/hip_runtime.h>
#include <cstdint>

#define D 128
#define BKT_SHIFT 8
#define EDGES_PER_BLOCK 4096

typedef __attribute__((ext_vector_type(8))) short short8;
typedef __attribute__((ext_vector_type(4))) float floatx4;

__device__ __forceinline__ float elu_f(float x) {
    return x > 0.0f ? x : __expf(x) - 1.0f;
}

__device__ __forceinline__ void split_bf16(float a, unsigned short& hi, unsigned short& lo) {
    unsigned u = __builtin_bit_cast(unsigned, a);
    unsigned hb = u & 0xffff0000u;
    float hf = __builtin_bit_cast(float, hb);
    float rl = a - hf;
    unsigned ul = __builtin_bit_cast(unsigned, rl);
    hi = (unsigned short)(u >> 16);
    lo = (unsigned short)(ul >> 16);
}

// ================= bucketed CSR build =================
__global__ __launch_bounds__(256) void bucket_count_kernel(
    const int* __restrict__ dst, int* __restrict__ bcnt, int E, int NB) {
    __shared__ int lcnt[512];
    int t = threadIdx.x;
    lcnt[t] = 0; lcnt[t + 256] = 0;
    __syncthreads();
    int base = blockIdx.x * EDGES_PER_BLOCK;
#pragma unroll
    for (int i = 0; i < 16; ++i) {
        int idx = base + i * 256 + t;
        if (idx < E) atomicAdd(&lcnt[dst[idx] >> BKT_SHIFT], 1);
    }
    __syncthreads();
    for (int b = t; b < NB; b += 256) {
        int c = lcnt[b];
        if (c) atomicAdd(&bcnt[b], c);
    }
}

__global__ __launch_bounds__(512) void scan_buckets_kernel(
    const int* __restrict__ bcnt, int* __restrict__ bucketoff,
    int* __restrict__ gcursor, int NB, int E, int* __restrict__ rowptr, int N) {
    __shared__ int s[512];
    int t = threadIdx.x;
    s[t] = (t < NB) ? bcnt[t] : 0;
    __syncthreads();
    for (int off = 1; off < 512; off <<= 1) {
        int v = (t >= off) ? s[t - off] : 0;
        __syncthreads();
        s[t] += v;
        __syncthreads();
    }
    int excl = (t == 0) ? 0 : s[t - 1];
    if (t < NB) { bucketoff[t] = excl; gcursor[t] = excl; }
    if (t == 0) { bucketoff[NB] = E; rowptr[N] = E; }
}

__global__ __launch_bounds__(256) void bucket_scatter_kernel(
    const int* __restrict__ src, const int* __restrict__ dst,
    int* __restrict__ gcursor, int2* __restrict__ staging, int E, int NB) {
    __shared__ int lcnt[512];
    __shared__ int lbase[512];
    int t = threadIdx.x;
    lcnt[t] = 0; lcnt[t + 256] = 0;
    __syncthreads();
    int base = blockIdx.x * EDGES_PER_BLOCK;
    int s_[16], d_[16], r_[16];
#pragma unroll
    for (int i = 0; i < 16; ++i) {
        int idx = base + i * 256 + t;
        if (idx < E) {
            s_[i] = src[idx];
            d_[i] = dst[idx];
            r_[i] = atomicAdd(&lcnt[d_[i] >> BKT_SHIFT], 1);
        }
    }
    __syncthreads();
    for (int b = t; b < NB; b += 256) {
        int c = lcnt[b];
        if (c) lbase[b] = atomicAdd(&gcursor[b], c);
    }
    __syncthreads();
#pragma unroll
    for (int i = 0; i < 16; ++i) {
        int idx = base + i * 256 + t;
        if (idx < E) {
            int bkt = d_[i] >> BKT_SHIFT;
            staging[lbase[bkt] + r_[i]] = make_int2(s_[i], d_[i]);
        }
    }
}

__global__ __launch_bounds__(256) void bucket_build_kernel(
    const int2* __restrict__ staging, const int* __restrict__ bucketoff,
    int* __restrict__ rowptr, int* __restrict__ col, int N) {
    __shared__ int hcnt[256];
    __shared__ int hoff[256];
    int t = threadIdx.x;
    int node0 = blockIdx.x << BKT_SHIFT;
    int off0 = bucketoff[blockIdx.x], off1 = bucketoff[blockIdx.x + 1];
    hcnt[t] = 0;
    __syncthreads();
    for (int i = off0 + t; i < off1; i += 256)
        atomicAdd(&hcnt[staging[i].y - node0], 1);
    __syncthreads();
    hoff[t] = hcnt[t];
    __syncthreads();
    for (int off = 1; off < 256; off <<= 1) {
        int u = (t >= off) ? hoff[t - off] : 0;
        __syncthreads();
        hoff[t] += u;
        __syncthreads();
    }
    int myoff = (t == 0) ? 0 : hoff[t - 1];
    __syncthreads();
    hoff[t] = myoff;
    hcnt[t] = 0;
    if (node0 + t < N) rowptr[node0 + t] = off0 + myoff;
    __syncthreads();
    for (int i = off0 + t; i < off1; i += 256) {
        int2 p = staging[i];
        int dl = p.y - node0;
        int pos = off0 + hoff[dl] + atomicAdd(&hcnt[dl], 1);
        col[pos] = p.x;
    }
}

// ---------------- GIN aggregation: fp32 out; col prefetch via shfl ----------------
__global__ __launch_bounds__(256) void aggregate_kernel(
    const float* __restrict__ h, const int* __restrict__ rowptr,
    const int* __restrict__ col, float* __restrict__ outp, int N) {
    int node = blockIdx.x * 8 + (threadIdx.x >> 5);
    int q = threadIdx.x & 31;
    if (node >= N) return;
    const float4* h4 = (const float4*)h;
    int e0 = rowptr[node], e1 = rowptr[node + 1];
    float4 acc = h4[(size_t)node * 32 + q];
    for (int eb = e0; eb < e1; eb += 32) {
        int m = e1 - eb; if (m > 32) m = 32;
        int cv = (q < m) ? col[eb + q] : 0;
        int j = 0;
        for (; j + 3 < m; j += 4) {
            int i0 = __shfl(cv, j, 32);
            int i1 = __shfl(cv, j + 1, 32);
            int i2 = __shfl(cv, j + 2, 32);
            int i3 = __shfl(cv, j + 3, 32);
            float4 v0 = h4[(size_t)i0 * 32 + q];
            float4 v1 = h4[(size_t)i1 * 32 + q];
            float4 v2 = h4[(size_t)i2 * 32 + q];
            float4 v3 = h4[(size_t)i3 * 32 + q];
            acc.x += (v0.x + v1.x) + (v2.x + v3.x);
            acc.y += (v0.y + v1.y) + (v2.y + v3.y);
            acc.z += (v0.z + v1.z) + (v2.z + v3.z);
            acc.w += (v0.w + v1.w) + (v2.w + v3.w);
        }
        for (; j < m; ++j) {
            int i0 = __shfl(cv, j, 32);
            float4 v = h4[(size_t)i0 * 32 + q];
            acc.x += v.x; acc.y += v.y; acc.z += v.z; acc.w += v.w;
        }
    }
    ((float4*)outp)[(size_t)node * 32 + q] = acc;
}

// ---------------- W prep: fragment-permuted bf16 hi/lo layout ----------------
// Wp[mat][tile(ks*8+nt2)][lane][j] = W[l][k*D+n], n=nt2*16+(lane&15), k=ks*32+(lane>>4)*8+j
__global__ void wprep_kernel(const float* __restrict__ W1, const float* __restrict__ W2,
                             unsigned short* __restrict__ Wph, unsigned short* __restrict__ Wpl,
                             int total) {
    int idx = blockIdx.x * 256 + threadIdx.x;
    if (idx >= total) return;
    int mat = idx >> 14;
    int rem = idx & 16383;
    int tile = rem >> 9;
    int lane = (rem >> 3) & 63;
    int j = rem & 7;
    int ks = tile >> 3, nt2 = tile & 7;
    int n = nt2 * 16 + (lane & 15);
    int k = ks * 32 + (lane >> 4) * 8 + j;
    int l = mat >> 1;
    const float* W = (mat & 1) ? W2 : W1;
    float v = W[(size_t)l * D * D + k * D + n];
    unsigned short h, lo;
    split_bf16(v, h, lo);
    Wph[idx] = h;
    Wpl[idx] = lo;
}

// ---------------- MFMA GEMM (split-bf16, 3 terms): out = [elu?](A' @ W + bias)
// A' = BN ? elu(Z*scale+shift) : Z   (Z fp32, split to bf16 hi/lo during staging)
template <bool BN, bool ELU_OUT, bool STATS>
__global__ __launch_bounds__(256, 3) void gemm_mfma(
    const float* __restrict__ Z,
    const unsigned short* __restrict__ Wph, const unsigned short* __restrict__ Wpl,
    const float* __restrict__ bias,
    const float* __restrict__ colsum_in, const float* __restrict__ gamma,
    const float* __restrict__ beta,
    float* __restrict__ outp, float* __restrict__ colsum_out, int N) {
    __shared__ unsigned short sAh[64 * 136];
    __shared__ unsigned short sAl[64 * 136];
    __shared__ float bnsum[2 * D];
    __shared__ float s_sc[D];
    __shared__ float s_sh[D];
    const int tid = threadIdx.x;
    const int row0 = blockIdx.x * 64;

    if (STATS && tid < 2 * D) bnsum[tid] = 0.f;

    if (BN) {
        if (tid < D) {
            float invN = 1.0f / (float)N;
            float mu = colsum_in[tid] * invN;
            float var = colsum_in[D + tid] * invN - mu * mu;
            float rs = rsqrtf(var + 1e-5f);
            float sc = gamma[tid] * rs;
            s_sc[tid] = sc;
            s_sh[tid] = beta[tid] - mu * sc;
        }
        __syncthreads();
    }
#pragma unroll
    for (int it = 0; it < 8; ++it) {
        int idx = tid + it * 256;
        int r = idx >> 5;
        int c4 = idx & 31;
        int gr = row0 + r;
        float4 v = make_float4(0.f, 0.f, 0.f, 0.f);
        if (gr < N) v = *(const float4*)&Z[(size_t)gr * D + c4 * 4];
        if (BN) {
            float4 sc = *(const float4*)&s_sc[c4 * 4];
            float4 sh = *(const float4*)&s_sh[c4 * 4];
            v.x = elu_f(v.x * sc.x + sh.x);
            v.y = elu_f(v.y * sc.y + sh.y);
            v.z = elu_f(v.z * sc.z + sh.z);
            v.w = elu_f(v.w * sc.w + sh.w);
        }
        ushort4 hh, ll;
        split_bf16(v.x, hh.x, ll.x);
        split_bf16(v.y, hh.y, ll.y);
        split_bf16(v.z, hh.z, ll.z);
        split_bf16(v.w, hh.w, ll.w);
        *(ushort4*)&sAh[r * 136 + c4 * 4] = hh;
        *(ushort4*)&sAl[r * 136 + c4 * 4] = ll;
    }
    __syncthreads();

    const int wave = tid >> 6, lane = tid & 63;
    const int wm = wave >> 1, wn = wave & 1;
    const int l15 = lane & 15, quad = lane >> 4;
    const short8* bph = (const short8*)Wph;
    const short8* bpl = (const short8*)Wpl;

    floatx4 acc[2][4];
#pragma unroll
    for (int mt = 0; mt < 2; ++mt)
#pragma unroll
        for (int nt = 0; nt < 4; ++nt)
            acc[mt][nt] = (floatx4){0.f, 0.f, 0.f, 0.f};

#pragma unroll
    for (int ks = 0; ks < 4; ++ks) {
        const int kf = ks * 32 + quad * 8;
        short8 bh[4], bl[4];
#pragma unroll
        for (int nt = 0; nt < 4; ++nt) {
            int tIdx = (ks * 8 + wn * 4 + nt) * 64 + lane;
            bh[nt] = bph[tIdx];
            bl[nt] = bpl[tIdx];
        }
        short8 ah[2], al[2];
#pragma unroll
        for (int mt = 0; mt < 2; ++mt) {
            int off = (wm * 32 + mt * 16 + l15) * 136 + kf;
            ah[mt] = *(const short8*)&sAh[off];
            al[mt] = *(const short8*)&sAl[off];
        }
#pragma unroll
        for (int mt = 0; mt < 2; ++mt)
#pragma unroll
            for (int nt = 0; nt < 4; ++nt) {
                acc[mt][nt] = __builtin_amdgcn_mfma_f32_16x16x32_bf16(ah[mt], bh[nt], acc[mt][nt], 0, 0, 0);
                acc[mt][nt] = __builtin_amdgcn_mfma_f32_16x16x32_bf16(ah[mt], bl[nt], acc[mt][nt], 0, 0, 0);
                acc[mt][nt] = __builtin_amdgcn_mfma_f32_16x16x32_bf16(al[mt], bh[nt], acc[mt][nt], 0, 0, 0);
            }
    }

#pragma unroll
    for (int nt = 0; nt < 4; ++nt) {
        int c = wn * 64 + nt * 16 + l15;
        float b = bias[c];
        float s = 0.f, s2 = 0.f;
#pragma unroll
        for (int mt = 0; mt < 2; ++mt) {
#pragma unroll
            for (int r = 0; r < 4; ++r) {
                int gm = row0 + wm * 32 + mt * 16 + quad * 4 + r;
                float v = acc[mt][nt][r] + b;
                if (ELU_OUT) v = elu_f(v);
                if (gm < N) {
                    outp[(size_t)gm * D + c] = v;
                    if (STATS) { s += v; s2 += v * v; }
                }
            }
        }
        if (STATS) {
            atomicAdd(&bnsum[c], s);
            atomicAdd(&bnsum[D + c], s2);
        }
    }
    if (STATS) {
        __syncthreads();
        if (tid < D) {
            atomicAdd(&colsum_out[tid], bnsum[tid]);
            atomicAdd(&colsum_out[D + tid], bnsum[D + tid]);
        }
    }
}

// ---------------- global mean pool ----------------
__global__ __launch_bounds__(128) void pool_kernel(
    const float* __restrict__ h, const int* __restrict__ batch,
    float* __restrict__ pooled, float* __restrict__ cnt, int N) {
    int c = threadIdx.x;
    int r0 = blockIdx.x * 256;
    if (r0 >= N) return;
    int rend = r0 + 256; if (rend > N) rend = N;
    int cur = batch[r0];
    float acc = 0.f;
    float cacc = 0.f;
    for (int r = r0; r < rend; ++r) {
        int b = batch[r];
        if (b != cur) {
            atomicAdd(&pooled[(size_t)cur * D + c], acc);
            if (c == 0) atomicAdd(&cnt[cur], cacc);
            acc = 0.f; cacc = 0.f; cur = b;
        }
        acc += h[(size_t)r * D + c];
        cacc += 1.f;
    }
    atomicAdd(&pooled[(size_t)cur * D + c], acc);
    if (c == 0) atomicAdd(&cnt[cur], cacc);
}

__global__ void final_linear_kernel(const float* __restrict__ pooled,
                                    const float* __restrict__ cnt,
                                    const float* __restrict__ linW,
                                    const float* __restrict__ linb,
                                    float* __restrict__ out, int G) {
    int t = blockIdx.x * blockDim.x + threadIdx.x;
    if (t >= G * 2) return;
    int g = t >> 1, o = t & 1;
    float inv = 1.0f / fmaxf(cnt[g], 1.0f);
    float s = linb[o];
    for (int c = 0; c < D; ++c)
        s += pooled[(size_t)g * D + c] * inv * linW[c * 2 + o];
    out[t] = s;
}

extern "C" void kernel_launch(void* const* d_in, const int* in_sizes, int n_in,
                              void* d_out, int out_size, void* d_ws, size_t ws_size,
                              hipStream_t stream) {
    const float* x      = (const float*)d_in[0];
    const int*  eidx    = (const int*)d_in[1];
    const int*  batch   = (const int*)d_in[2];
    const float* W1     = (const float*)d_in[3];
    const float* b1     = (const float*)d_in[4];
    const float* gamma  = (const float*)d_in[5];
    const float* beta   = (const float*)d_in[6];
    const float* W2     = (const float*)d_in[7];
    const float* b2     = (const float*)d_in[8];
    const float* linW   = (const float*)d_in[9];
    const float* linb   = (const float*)d_in[10];
    float* out = (float*)d_out;

    const int N = in_sizes[0] / D;
    const int E = in_sizes[1] / 2;
    const int L = in_sizes[3] / (D * D);
    const int G = out_size / 2;
    const int* esrc = eidx;
    const int* edst = eidx + E;
    const int NB = (N + 255) >> 8;

    size_t off = 0;
    auto carve = [&](size_t bytes) -> void* {
        void* p = (char*)d_ws + off;
        off += (bytes + 255) & ~(size_t)255;
        return p;
    };
    const size_t ND = (size_t)N * D;
    const int WTOT = 2 * L * D * D;
    float* agg    = (float*)carve(ND * 4);
    float* z1     = (float*)carve(ND * 4);           // also aliased as CSR staging
    float* hbuf   = (float*)carve(ND * 4);
    unsigned short* Wph = (unsigned short*)carve((size_t)WTOT * 2);
    unsigned short* Wpl = (unsigned short*)carve((size_t)WTOT * 2);
    int* rowptr   = (int*)carve((size_t)(N + 1) * 4);
    int* col      = (int*)carve((size_t)E * 4);
    int* bcnt     = (int*)carve(512 * 4);            // contiguous with colsum4: one memset
    float* colsum4 = (float*)carve((size_t)4 * 2 * D * 4);
    int* bucketoff = (int*)carve(513 * 4);
    int* gcursor  = (int*)carve(512 * 4);
    float* pooled = (float*)carve((size_t)G * D * 4); // contiguous with cnt: one memset
    float* cnt    = (float*)carve((size_t)G * 4);
    int2* staging = (int2*)z1;
    (void)ws_size; (void)n_in;

    hipMemsetAsync(bcnt, 0, 512 * 4 + (size_t)4 * 2 * D * 4, stream);
    hipMemsetAsync(pooled, 0, (size_t)G * D * 4 + (size_t)G * 4, stream);

    const int EB = (E + EDGES_PER_BLOCK - 1) / EDGES_PER_BLOCK;
    bucket_count_kernel<<<EB, 256, 0, stream>>>(edst, bcnt, E, NB);
    scan_buckets_kernel<<<1, 512, 0, stream>>>(bcnt, bucketoff, gcursor, NB, E, rowptr, N);
    bucket_scatter_kernel<<<EB, 256, 0, stream>>>(esrc, edst, gcursor, staging, E, NB);
    bucket_build_kernel<<<NB, 256, 0, stream>>>(staging, bucketoff, rowptr, col, N);
    wprep_kernel<<<(WTOT + 255) / 256, 256, 0, stream>>>(W1, W2, Wph, Wpl, WTOT);

    const int gemm_grid = (N + 63) / 64;
    const int agg_grid = (N + 7) / 8;
    const float* hin = x;
    for (int l = 0; l < L; ++l) {
        float* colsum = colsum4 + (size_t)l * 2 * D;
        aggregate_kernel<<<agg_grid, 256, 0, stream>>>(hin, rowptr, col, agg, N);
        gemm_mfma<false, false, true><<<gemm_grid, 256, 0, stream>>>(
            agg,
            Wph + (size_t)(l * 2) * D * D, Wpl + (size_t)(l * 2) * D * D,
            b1 + (size_t)l * D, nullptr, nullptr, nullptr, z1, colsum, N);
        gemm_mfma<true, true, false><<<gemm_grid, 256, 0, stream>>>(
            z1,
            Wph + (size_t)(l * 2 + 1) * D * D, Wpl + (size_t)(l * 2 + 1) * D * D,
            b2 + (size_t)l * D, colsum, gamma + (size_t)l * D, beta + (size_t)l * D,
            hbuf, nullptr, N);
        hin = hbuf;
    }

    pool_kernel<<<(N + 255) / 256, 128, 0, stream>>>(hbuf, batch, pooled, cnt, N);
    final_linear_kernel<<<(G * 2 + 255) / 256, 256, 0, stream>>>(pooled, cnt, linW, linb, out, G);
}